// Round 9
// baseline (243.277 us; speedup 1.0000x reference)
//
#include <hip/hip_runtime.h>

// CrossWinAttention on MI355X (gfx950), bf16 MFMA pipeline. R9:
//  - k_lnproj rewritten: A-fragments loaded DIRECTLY from global fp32 into
//    registers (2 float4 per row per ks; rows lm/lm+32 per lane) — no A-LDS
//    stage, no staging barrier. LN stats accumulated in-flight per lane and
//    completed with one shfl_xor(32) (row halves live in lane pairs (lm,0)/
//    (lm,1)); only a 512 B LDS broadcast remains (C-rows != A-rows). LDS
//    17.5 KB -> 0.5 KB, 2 barriers -> 1, occupancy unbound from LDS.
//  - k_attn reverted EXACTLY to R7 (47.5 us, best of 7 structural variants;
//    R8's dual-tile was 49.4). k_attn declared at empirical floor for this
//    decomposition — counters cannot attribute the remaining stall.
//  - k_prep / k_out unchanged.
//  - Carried: S^T trick (P stays in registers), V^T key-swizzled in LDS,
//    K from global, LN folded into GEMM epilogue, mean-over-N folded before
//    final projection, scale*log2e folded into wq/bq (exp2-only softmax),
//    v_exp_f32 + hw bf16 cvt.

typedef unsigned short u16;
typedef __bf16 bf16x8 __attribute__((ext_vector_type(8)));
typedef __bf16 bf16x4 __attribute__((ext_vector_type(4)));
typedef float  f32x16 __attribute__((ext_vector_type(16)));
typedef unsigned short u16x8 __attribute__((ext_vector_type(8)));
typedef unsigned short u16x4 __attribute__((ext_vector_type(4)));

union U8 { u16x8 u; bf16x8 b; u16x4 h[2]; };

#if __has_builtin(__builtin_amdgcn_exp2f)
#define EXP2(x) __builtin_amdgcn_exp2f(x)
#else
#define EXP2(x) exp2f(x)
#endif

__device__ __forceinline__ f32x16 mfma_bf16(bf16x8 a, bf16x8 b, f32x16 c){
  return __builtin_amdgcn_mfma_f32_32x32x16_bf16(a, b, c, 0, 0, 0);
}

// 32x32x16 bf16 fragment conventions:
//  A: m=lane&31, k=(lane>>5)*8+j ; B: n=lane&31, k=(lane>>5)*8+j
//  C/D: col=lane&31, row=(reg&3)+8*(reg>>2)+4*(lane>>5)   [verified m74/m101]
// S^T = mfma(K, Q): col = q (fixed per lane), reg axis = keys; regs 0..7 are
// exactly the PV A-slots for keys 4lh+{0-3,8-11}, regs 8..15 for +16. V^T is
// stored with the matching key swizzle so PV B-fragments are single 16B reads.

// ---------------------------------------------------------------- k_prep
// 4 blocks (one per weight) x 512 thr. Coalesced load -> LDS -> transposed
// bf16 write + parallel bias'/u reduction.
__global__ __launch_bounds__(512) void k_prep(
    const float* __restrict__ wq, const float* __restrict__ bq,
    const float* __restrict__ gq, const float* __restrict__ betq,
    const float* __restrict__ wk, const float* __restrict__ bk,
    const float* __restrict__ gk, const float* __restrict__ betk,
    const float* __restrict__ wv, const float* __restrict__ bv,
    const float* __restrict__ gv, const float* __restrict__ betv,
    const float* __restrict__ wp,
    u16* __restrict__ wqT, u16* __restrict__ wkT, u16* __restrict__ wvT, u16* __restrict__ wpT,
    float* __restrict__ bq2, float* __restrict__ bk2, float* __restrict__ bv2,
    float* __restrict__ uq2, float* __restrict__ uk2, float* __restrict__ uv2)
{
  __shared__ float wls[128*129];
  __shared__ float gls[128], bls[128];
  __shared__ float redb[512], redu[512];
  const float ALPHA_Q = 0.17677669529663687f * 1.4426950408889634f; // DH^-0.5 * log2(e)
  int wsel = blockIdx.x, tid = threadIdx.x;
  const float *w, *bb, *g, *bet; u16* wT; float *b2, *u2; float alpha;
  if (wsel == 0){ w=wq; bb=bq; g=gq; bet=betq; wT=wqT; b2=bq2; u2=uq2; alpha=ALPHA_Q; }
  else if (wsel == 1){ w=wk; bb=bk; g=gk; bet=betk; wT=wkT; b2=bk2; u2=uk2; alpha=1.f; }
  else if (wsel == 2){ w=wv; bb=bv; g=gv; bet=betv; wT=wvT; b2=bv2; u2=uv2; alpha=1.f; }
  else { w=wp; bb=nullptr; g=nullptr; bet=nullptr; wT=wpT; b2=nullptr; u2=nullptr; alpha=1.f; }

  if (tid < 128){
    gls[tid] = g ? g[tid] : 1.f;
    bls[tid] = bet ? bet[tid] : 0.f;
  }
  const float4* w4 = (const float4*)w;
  #pragma unroll
  for (int i = 0; i < 8; i++){
    int idx = tid + i*512;              // 4096 float4s
    int row = idx >> 5, c4 = (idx & 31) * 4;   // row = k, c4 = n base
    float4 x = w4[idx];
    wls[row*129 + c4 + 0] = x.x;
    wls[row*129 + c4 + 1] = x.y;
    wls[row*129 + c4 + 2] = x.z;
    wls[row*129 + c4 + 3] = x.w;
  }
  __syncthreads();
  int n = tid >> 2, qp = tid & 3;
  float sb = 0.f, su = 0.f;
  alignas(16) __bf16 tmp[32];
  #pragma unroll
  for (int kk = 0; kk < 32; kk++){
    int k2 = qp*32 + kk;
    float wv_ = wls[k2*129 + n];
    float gv_ = gls[k2];
    sb += bls[k2] * wv_;
    su += gv_ * wv_;
    tmp[kk] = (__bf16)(wv_ * gv_ * alpha);
  }
  #pragma unroll
  for (int j = 0; j < 4; j++)
    *(bf16x8*)(wT + n*128 + qp*32 + j*8) = *(bf16x8*)&tmp[j*8];
  redb[tid] = sb; redu[tid] = su;
  __syncthreads();
  if (qp == 0 && bb){
    float s = bb[n] + redb[tid] + redb[tid+1] + redb[tid+2] + redb[tid+3];
    float u = redu[tid] + redu[tid+1] + redu[tid+2] + redu[tid+3];
    b2[n] = s * alpha;
    u2[n] = u * alpha;
  }
}

// ---------------------------------------------------------------- k_lnproj
// grid 2304 = 128 (b,l) * 6 (n) * 3 (q/k/v); 256 thr (4 waves).
// Direct-to-fragment A loads (no LDS stage): lane (lm,lh) loads rows lm &
// lm+32, cols ks*16+lh*8+0..7 (two float4 per row per ks), cvt to bf16
// in-reg, MFMA on raw x; LN stats in-flight + shfl_xor(32); 512 B LDS
// broadcast for C-row stats; LN applied in epilogue y = rs*z - rm*u2 + b2.
__global__ __launch_bounds__(256) void k_lnproj(
    const float* __restrict__ qg, const float* __restrict__ kg, const float* __restrict__ vg,
    const u16* __restrict__ wqT, const u16* __restrict__ wkT, const u16* __restrict__ wvT,
    const float* __restrict__ bq2, const float* __restrict__ bk2, const float* __restrict__ bv2,
    const float* __restrict__ uq2, const float* __restrict__ uk2, const float* __restrict__ uv2,
    u16* __restrict__ qh, u16* __restrict__ kh, u16* __restrict__ vh)
{
  __shared__ float rs_s[64], rm_s[64];
  int bid = blockIdx.x, tid = threadIdx.x;
  int which = bid % 3;
  int t = bid / 3;
  int n = t % 6, bl = t / 6;
  const float* src; const u16* wT; const float *b2, *u2; u16* dstb;
  if (which == 0){ src=qg; wT=wqT; b2=bq2; u2=uq2; dstb=qh; }
  else if (which == 1){ src=kg; wT=wkT; b2=bk2; u2=uk2; dstb=kh; }
  else { src=vg; wT=wvT; b2=bv2; u2=uv2; dstb=vh; }
  int b = bl >> 6, l = bl & 63;
  const float4* s4 = (const float4*)(src + (size_t)((b*6 + n)*64 + l)*64*128);

  int wave = tid >> 6, lane = tid & 63, lm = lane & 31, lh = lane >> 5;

  // B fragments (weight cols 32*wave..+31), L2-resident
  bf16x8 bfr[8];
  const u16* wrow = wT + (32*wave + lm)*128 + lh*8;
  #pragma unroll
  for (int ks = 0; ks < 8; ks++) bfr[ks] = *(const bf16x8*)(wrow + ks*16);

  f32x16 acc0, acc1;
  #pragma unroll
  for (int r = 0; r < 16; r++){ acc0[r]=0.f; acc1[r]=0.f; }
  float s1a = 0.f, s2a = 0.f, s1b = 0.f, s2b = 0.f;

  // rows lm (acc0) and lm+32 (acc1); per ks: cols ks*16 + lh*8 + 0..7
  const float4* rowa = s4 + (size_t)lm*32 + lh*2;
  const float4* rowb = rowa + 32*32;
  #pragma unroll
  for (int ks = 0; ks < 8; ks++){
    float4 fa0 = rowa[ks*4];
    float4 fa1 = rowa[ks*4 + 1];
    float4 fb0 = rowb[ks*4];
    float4 fb1 = rowb[ks*4 + 1];
    s1a += (fa0.x + fa0.y + fa0.z + fa0.w) + (fa1.x + fa1.y + fa1.z + fa1.w);
    s2a += fa0.x*fa0.x + fa0.y*fa0.y + fa0.z*fa0.z + fa0.w*fa0.w
         + fa1.x*fa1.x + fa1.y*fa1.y + fa1.z*fa1.z + fa1.w*fa1.w;
    s1b += (fb0.x + fb0.y + fb0.z + fb0.w) + (fb1.x + fb1.y + fb1.z + fb1.w);
    s2b += fb0.x*fb0.x + fb0.y*fb0.y + fb0.z*fb0.z + fb0.w*fb0.w
         + fb1.x*fb1.x + fb1.y*fb1.y + fb1.z*fb1.z + fb1.w*fb1.w;
    U8 a0, a1;
    a0.b[0] = (__bf16)fa0.x; a0.b[1] = (__bf16)fa0.y;
    a0.b[2] = (__bf16)fa0.z; a0.b[3] = (__bf16)fa0.w;
    a0.b[4] = (__bf16)fa1.x; a0.b[5] = (__bf16)fa1.y;
    a0.b[6] = (__bf16)fa1.z; a0.b[7] = (__bf16)fa1.w;
    a1.b[0] = (__bf16)fb0.x; a1.b[1] = (__bf16)fb0.y;
    a1.b[2] = (__bf16)fb0.z; a1.b[3] = (__bf16)fb0.w;
    a1.b[4] = (__bf16)fb1.x; a1.b[5] = (__bf16)fb1.y;
    a1.b[6] = (__bf16)fb1.z; a1.b[7] = (__bf16)fb1.w;
    acc0 = mfma_bf16(a0.b, bfr[ks], acc0);
    acc1 = mfma_bf16(a1.b, bfr[ks], acc1);
  }

  // finish stats: lh halves of each row combine via xor-32
  s1a += __shfl_xor(s1a, 32, 64);
  s2a += __shfl_xor(s2a, 32, 64);
  s1b += __shfl_xor(s1b, 32, 64);
  s2b += __shfl_xor(s2b, 32, 64);
  if (wave == 0 && lh == 0){
    float ma = s1a * (1.f/128.f);
    float ra = rsqrtf(s2a * (1.f/128.f) - ma*ma + 1e-5f);
    rs_s[lm] = ra;  rm_s[lm] = ra * ma;
    float mb = s1b * (1.f/128.f);
    float rb = rsqrtf(s2b * (1.f/128.f) - mb*mb + 1e-5f);
    rs_s[lm+32] = rb;  rm_s[lm+32] = rb * mb;
  }
  __syncthreads();

  int col = 32*wave + lm;
  float u2c = u2[col], bc = b2[col];
  u16* dst = dstb + ((size_t)(bl*4 + wave)*384 + n*64)*32 + lm;
  #pragma unroll
  for (int r = 0; r < 16; r++){
    int row0 = (r&3) + 8*(r>>2) + 4*lh;
    float y0 = rs_s[row0]     * acc0[r] - rm_s[row0]     * u2c + bc;
    float y1 = rs_s[row0+32]  * acc1[r] - rm_s[row0+32]  * u2c + bc;
    *(__bf16*)&dst[(size_t)row0*32]      = (__bf16)y0;
    *(__bf16*)&dst[(size_t)(32+row0)*32] = (__bf16)y1;
  }
}

// ---------------------------------------------------------------- k_attn
// R7-exact: grid 512 = (b,l)*h; 384 thr = 6 waves; wave w = n (owns all 64
// q rows: groups A/B). K from global; V^T key-swizzled in LDS. LDS 34.3 KB.
__global__ __launch_bounds__(384) void k_attn(
    const u16* __restrict__ qh, const u16* __restrict__ kh, const u16* __restrict__ vh,
    u16* __restrict__ abar)
{
  __shared__ alignas(16) u16 vts[32*408];   // V^T [dh][swizzled key], stride 408
  __shared__ float abar_s[64*32];
  int bid = blockIdx.x, tid = threadIdx.x;
  int h = bid & 3, bl = bid >> 2;
  const u16* qb = qh + (size_t)bid * (384*32);
  const u16* kb = kh + (size_t)bid * (384*32);
  const u16* vb = vh + (size_t)bid * (384*32);

  int wave = tid >> 6, lane = tid & 63, lm = lane & 31, lh = lane >> 5;
  int n = wave;                       // 6 waves == 6 views

  // Q fragments: group A = q rows n*64+lm, group B = +32 (independent of LDS)
  const u16* qbase = qb + (size_t)(n*64 + lm)*32 + lh*8;
  bf16x8 qfA0 = *(const bf16x8*)(qbase);
  bf16x8 qfA1 = *(const bf16x8*)(qbase + 16);
  bf16x8 qfB0 = *(const bf16x8*)(qbase + 32*32);
  bf16x8 qfB1 = *(const bf16x8*)(qbase + 32*32 + 16);

  // stage V transposed + key-swizzled: key u (mod 32) at a-group perm{0,2,1,3,4,6,5,7}
  #pragma unroll
  for (int i = 0; i < 4; i++){
    int c = tid + i*384;               // 1536 16B chunks
    int key = c >> 2, part = c & 3;
    int u = key & 31, tt = key >> 5;
    int a = u >> 2;
    int anew = (a & 4) | ((a & 1) << 1) | ((a >> 1) & 1);
    int pos = tt*32 + anew*4 + (u & 3);
    u16x8 vv = *(const u16x8*)(vb + key*32 + part*8);
    #pragma unroll
    for (int jj = 0; jj < 8; jj++) vts[(part*8 + jj)*408 + pos] = vv[jj];
  }
  for (int idx = tid; idx < 2048; idx += 384) abar_s[idx] = 0.f;
  __syncthreads();

  const u16* vrow = &vts[lm*408 + 8*lh];
  const u16* krow = kb + lm*32 + lh*8;

  f32x16 oA, oB;
  #pragma unroll
  for (int r = 0; r < 16; r++){ oA[r] = 0.f; oB[r] = 0.f; }
  float sleA = 0.f, sleB = 0.f;

  #pragma unroll
  for (int kt = 0; kt < 12; kt++){
    bf16x8 kf0 = *(const bf16x8*)(krow + kt*(32*32));
    bf16x8 kf1 = *(const bf16x8*)(krow + kt*(32*32) + 16);
    f32x16 sa, sb_;
    #pragma unroll
    for (int r = 0; r < 16; r++){ sa[r] = 0.f; sb_[r] = 0.f; }
    sa  = mfma_bf16(kf0, qfA0, sa);      // two independent chains (A/B)
    sb_ = mfma_bf16(kf0, qfB0, sb_);
    sa  = mfma_bf16(kf1, qfA1, sa);
    sb_ = mfma_bf16(kf1, qfB1, sb_);
    U8 v0, v1;
    v0.u = *(const u16x8*)(vrow + kt*32);
    v1.u = *(const u16x8*)(vrow + kt*32 + 16);
    U8 pA0, pA1, pB0, pB1;
    #pragma unroll
    for (int r = 0; r < 8; r++){
      float eA0 = EXP2(sa[r]);
      float eA1 = EXP2(sa[r+8]);
      float eB0 = EXP2(sb_[r]);
      float eB1 = EXP2(sb_[r+8]);
      sleA += eA0 + eA1;
      sleB += eB0 + eB1;
      pA0.b[r] = (__bf16)eA0;            // v_cvt_pk_bf16_f32 (RNE)
      pA1.b[r] = (__bf16)eA1;
      pB0.b[r] = (__bf16)eB0;
      pB1.b[r] = (__bf16)eB1;
    }
    oA = mfma_bf16(pA0.b, v0.b, oA);
    oB = mfma_bf16(pB0.b, v0.b, oB);
    oA = mfma_bf16(pA1.b, v1.b, oA);
    oB = mfma_bf16(pB1.b, v1.b, oB);
  }

  // row sums: combine lh halves, broadcast reciprocals (1/6 = mean over n)
  sleA += __shfl_xor(sleA, 32, 64);
  sleB += __shfl_xor(sleB, 32, 64);
  float invA = (1.f/6.f) / sleA;
  float invB = (1.f/6.f) / sleB;

  // o lane(lm,lh) reg r = O[q = (r&3)+8*(r>>2)+4*lh][dh = lm]; w12 = q (A), 32+q (B)
  #pragma unroll
  for (int r = 0; r < 16; r++){
    int q_l = (r&3) + 8*(r>>2) + 4*lh;
    float a = oA[r] * __shfl(invA, q_l, 64);
    float b = oB[r] * __shfl(invB, q_l, 64);
    atomicAdd(&abar_s[q_l*32 + lm], a);
    atomicAdd(&abar_s[(32 + q_l)*32 + lm], b);
  }
  __syncthreads();
  u16* ob = abar + (size_t)(bl*64)*128 + h*32;
  for (int idx = tid; idx < 2048; idx += 384){
    int w12 = idx >> 5, dh = idx & 31;
    *(__bf16*)&ob[(size_t)w12*128 + dh] = (__bf16)abar_s[idx];
  }
}

// ---------------------------------------------------------------- k_out
__global__ __launch_bounds__(256) void k_out(
    const u16* __restrict__ abar, const u16* __restrict__ wpT,
    const float* __restrict__ bp, const float* __restrict__ skip,
    float* __restrict__ out)
{
  __shared__ alignas(16) u16 Als[64*136];
  int tid = threadIdx.x;
  int R0 = blockIdx.x * 64;
  #pragma unroll
  for (int i = 0; i < 4; i++){
    int c = tid + i*256;
    int row = c >> 4, part = c & 15;
    *(u16x8*)&Als[row*136 + part*8] = *(const u16x8*)(abar + (size_t)(R0+row)*128 + part*8);
  }
  __syncthreads();
  int wave = tid >> 6, lane = tid & 63, lm = lane & 31, lh = lane >> 5;
  bf16x8 bfr[8];
  const u16* wrow = wpT + (32*wave + lm)*128 + lh*8;
  #pragma unroll
  for (int ks = 0; ks < 8; ks++) bfr[ks] = *(const bf16x8*)(wrow + ks*16);
  f32x16 acc0, acc1;
  #pragma unroll
  for (int r = 0; r < 16; r++){ acc0[r]=0.f; acc1[r]=0.f; }
  #pragma unroll
  for (int ks = 0; ks < 8; ks++){
    bf16x8 a0 = *(const bf16x8*)&Als[lm*136      + ks*16 + lh*8];
    bf16x8 a1 = *(const bf16x8*)&Als[(32+lm)*136 + ks*16 + lh*8];
    acc0 = mfma_bf16(a0, bfr[ks], acc0);
    acc1 = mfma_bf16(a1, bfr[ks], acc1);
  }
  float bias = bp[32*wave + lm];
  #pragma unroll
  for (int r = 0; r < 16; r++){
    int row0 = (r&3) + 8*(r>>2) + 4*lh;
    size_t f0 = (size_t)(R0 + row0)*128 + 32*wave + lm;
    out[f0] = acc0[r] + bias + skip[f0];
    size_t f1 = (size_t)(R0 + 32 + row0)*128 + 32*wave + lm;
    out[f1] = acc1[r] + bias + skip[f1];
  }
}

// ---------------------------------------------------------------- launch
extern "C" void kernel_launch(void* const* d_in, const int* in_sizes, int n_in,
                              void* d_out, int out_size, void* d_ws, size_t ws_size,
                              hipStream_t stream)
{
  const float* q    = (const float*)d_in[0];
  const float* k    = (const float*)d_in[1];
  const float* v    = (const float*)d_in[2];
  const float* skip = (const float*)d_in[3];
  const float* gq   = (const float*)d_in[4];
  const float* betq = (const float*)d_in[5];
  const float* gk   = (const float*)d_in[6];
  const float* betk = (const float*)d_in[7];
  const float* gv   = (const float*)d_in[8];
  const float* betv = (const float*)d_in[9];
  const float* wq   = (const float*)d_in[10];
  const float* bq   = (const float*)d_in[11];
  const float* wk   = (const float*)d_in[12];
  const float* bk   = (const float*)d_in[13];
  const float* wv   = (const float*)d_in[14];
  const float* bv   = (const float*)d_in[15];
  const float* wp   = (const float*)d_in[16];
  const float* bp   = (const float*)d_in[17];
  float* out = (float*)d_out;

  char* ws = (char*)d_ws;
  u16* wqT = (u16*)ws;                 // 16384 u16 each
  u16* wkT = wqT + 16384;
  u16* wvT = wkT + 16384;
  u16* wpT = wvT + 16384;
  float* bq2 = (float*)(ws + 131072);  // 128 f32 each
  float* bk2 = bq2 + 128;
  float* bv2 = bk2 + 128;
  float* uq2 = bv2 + 128;
  float* uk2 = uq2 + 128;
  float* uv2 = uk2 + 128;
  u16* qh = (u16*)(ws + 134144);       // [128][4][384][32] bf16 = 12.58 MB each
  u16* kh = qh + 6291456;
  u16* vh = kh + 6291456;
  u16* abar = vh + 6291456;            // [8192][128] bf16 = 2 MB

  k_prep  <<<4,    512, 0, stream>>>(wq,bq,gq,betq, wk,bk,gk,betk, wv,bv,gv,betv, wp,
                                     wqT,wkT,wvT,wpT, bq2,bk2,bv2, uq2,uk2,uv2);
  k_lnproj<<<2304, 256, 0, stream>>>(q,k,v, wqT,wkT,wvT, bq2,bk2,bv2, uq2,uk2,uv2, qh,kh,vh);
  k_attn  <<<512,  384, 0, stream>>>(qh,kh,vh, abar);
  k_out   <<<128,  256, 0, stream>>>(abar, wpT, bp, skip, out);
}